// Round 2
// 672.504 us; speedup vs baseline: 1.2108x; 1.2108x over previous
//
#include <hip/hip_runtime.h>

#define N_NODES 100000
#define N_EDGES 3200000
#define DIM 256

#define BROWS 256                 // rows per bucket
#define NBUCK 391                 // ceil(N_NODES / BROWS)

typedef short short8 __attribute__((ext_vector_type(8)));
typedef float f32x4 __attribute__((ext_vector_type(4)));

static __device__ __forceinline__ unsigned short f2bf(float f) {
    unsigned int u = __float_as_uint(f);
    u = (u + 0x7FFFu + ((u >> 16) & 1u)) >> 16;   // RNE
    return (unsigned short)u;
}

// ---------------- CSR build ----------------
__global__ void k_hist(const int* __restrict__ row, int* __restrict__ cnt) {
    int e = blockIdx.x * 256 + threadIdx.x;
    atomicAdd(&cnt[row[e]], 1);
}

__global__ void k_scan1(const int* __restrict__ cnt, int* __restrict__ rs,
                        int* __restrict__ bsum) {
    __shared__ int lds[1024];
    int t = threadIdx.x;
    int g = blockIdx.x * 1024 + t;
    int x = cnt[g];
    lds[t] = x;
    __syncthreads();
    for (int off = 1; off < 1024; off <<= 1) {
        int v = (t >= off) ? lds[t - off] : 0;
        __syncthreads();
        lds[t] += v;
        __syncthreads();
    }
    rs[g] = lds[t] - x;                 // exclusive
    if (t == 1023) bsum[blockIdx.x] = lds[t];
}

__global__ void k_scan2(int* __restrict__ bsum) {   // 1 block, 128 thr, 98 valid
    __shared__ int lds[128];
    int t = threadIdx.x;
    int x = (t < 98) ? bsum[t] : 0;
    lds[t] = x;
    __syncthreads();
    for (int off = 1; off < 128; off <<= 1) {
        int v = (t >= off) ? lds[t - off] : 0;
        __syncthreads();
        lds[t] += v;
        __syncthreads();
    }
    if (t < 98) bsum[t] = lds[t] - x;   // exclusive
}

__global__ void k_scanadd(int* __restrict__ rs, const int* __restrict__ bsum) {
    int g = blockIdx.x * 1024 + threadIdx.x;
    rs[g] = rs[g] + bsum[blockIdx.x];
}

// bucket cursors start at rs[bucket * BROWS]
__global__ void k_binit(const int* __restrict__ rs, int* __restrict__ bcur) {
    int t = threadIdx.x;
    if (t < NBUCK) bcur[t] = rs[t * BROWS];
}

// Pass 1: block-local counting scatter into per-(block,bucket) contiguous
// sub-segments of tmp. All writers of a cache line are in one block => line is
// assembled inside a single XCD's L2 => ~1 writeback per line (vs 8 for the
// old fully-random cross-XCD 8B scatter, which showed 198 MB WRITE_SIZE).
__global__ __launch_bounds__(512) void k_bucket(const int* __restrict__ row,
                                                const int* __restrict__ col,
                                                const float* __restrict__ val,
                                                int* __restrict__ bcur,
                                                int2* __restrict__ tmp) {
    __shared__ int hist[NBUCK];
    __shared__ int base[NBUCK];
    int t = threadIdx.x;
    const int per = (N_EDGES + gridDim.x - 1) / gridDim.x;   // 12500 @ grid=256
    int e0 = blockIdx.x * per;
    int e1 = min(e0 + per, N_EDGES);
    for (int i = t; i < NBUCK; i += 512) hist[i] = 0;
    __syncthreads();
    for (int e = e0 + t; e < e1; e += 512)
        atomicAdd(&hist[row[e] >> 8], 1);
    __syncthreads();
    for (int i = t; i < NBUCK; i += 512) {
        int c = hist[i];
        base[i] = c ? atomicAdd(&bcur[i], c) : 0;
        hist[i] = 0;                     // reuse as local cursor
    }
    __syncthreads();
    for (int e = e0 + t; e < e1; e += 512) {
        int r = row[e];
        int b = r >> 8;                  // bucket (BROWS = 256)
        int off = atomicAdd(&hist[b], 1);
        // pack: col in bits [0,17), local row in bits [17,25)
        tmp[base[b] + off] = make_int2(((r & 255) << 17) | col[e],
                                       __float_as_int(val[e]));
    }
}

// Pass 2: one block per bucket; place edges at final CSR positions via LDS
// per-row cursors. Random writes confined to this bucket's ~64 KB window,
// all from one block => lines fully assembled in one L2.
__global__ __launch_bounds__(256) void k_place(const int* __restrict__ rs,
                                               const int2* __restrict__ tmp,
                                               int2* __restrict__ csr) {
    __shared__ int lcur[BROWS];
    int t = threadIdx.x;
    int rowbase = blockIdx.x * BROWS;
    int rr = rowbase + t;
    lcur[t] = (rr < N_NODES) ? rs[rr] : 0;
    __syncthreads();
    int s = rs[rowbase];
    int e = rs[min(rowbase + BROWS, N_NODES)];
    for (int i = s + t; i < e; i += 256) {
        int2 x = tmp[i];
        int pos = atomicAdd(&lcur[x.x >> 17], 1);
        csr[pos] = make_int2(x.x & 0x1FFFF, x.y);
    }
}

// ---------------- W pack (fp32 -> bf16 fragment layout) ----------------
// wp[((kc*16+mt)*64+lane)*8 + j] = bf16( W[(kc*32 + (lane>>4)*8 + j)][mt*16 + (lane&15)] )
// Serves as the A-fragment (W^T) of the transposed GEMM.
__global__ void k_wpack(const float* __restrict__ W, unsigned short* __restrict__ wp) {
    int t = blockIdx.x * 256 + threadIdx.x;     // 0..8191
    int lane = t & 63;
    int nt = (t >> 6) & 15;
    int kc = t >> 10;
    int n = nt * 16 + (lane & 15);
    int kbase = kc * 32 + ((lane >> 4) << 3);
    unsigned short* dst = wp + (size_t)t * 8;
#pragma unroll
    for (int j = 0; j < 8; j++) dst[j] = f2bf(W[(size_t)(kbase + j) * DIM + n]);
}

// ---------------- GEMM: sup(bf16) = X @ W, computed as (X@W)^T tiles ----------------
// block = 1024 thr = 16 waves; wave handles 16 nodes x 256 dims; strip = 256 nodes.
// Epilogue bounces through LDS so every global store writes 1 KB contiguous.
#define LDSTRIDE 528                       // 512 + 16 pad (bank spread), 8B-aligned
__global__ __launch_bounds__(1024, 4) void k_gemm(const float* __restrict__ X,
                                                  const unsigned short* __restrict__ wp,
                                                  unsigned short* __restrict__ sup) {
    __shared__ char pool[16 * 16 * LDSTRIDE];   // 135168 B; W uses first 131072 B
    unsigned short* wlds = (unsigned short*)pool;
    int t = threadIdx.x;
    int wave = t >> 6, lane = t & 63;
    int q = lane >> 4, nl = lane & 15;

    const int nstrips = (N_NODES + 255) / 256;  // 391
    for (int s = blockIdx.x; s < nstrips; s += gridDim.x) {
        // stage full packed W into LDS (clobbered by previous epilogue)
        for (int i = t; i < 8192; i += 1024)
            ((uint4*)wlds)[i] = ((const uint4*)wp)[i];
        __syncthreads();

        int rowbase = s * 256 + wave * 16;
        f32x4 acc[16];
#pragma unroll
        for (int mt = 0; mt < 16; mt++) acc[mt] = (f32x4){0.f, 0.f, 0.f, 0.f};

        for (int kc = 0; kc < 8; kc++) {
            // B-fragment: X row (node = rowbase + nl), k = kc*32 + q*8 + j
            int r = rowbase + nl;
            short8 b = (short8)0;
            if (r < N_NODES) {
                const float* bp = X + (size_t)r * DIM + kc * 32 + (q << 3);
                float4 b0 = *(const float4*)bp;
                float4 b1 = *(const float4*)(bp + 4);
                b[0] = (short)f2bf(b0.x); b[1] = (short)f2bf(b0.y);
                b[2] = (short)f2bf(b0.z); b[3] = (short)f2bf(b0.w);
                b[4] = (short)f2bf(b1.x); b[5] = (short)f2bf(b1.y);
                b[6] = (short)f2bf(b1.z); b[7] = (short)f2bf(b1.w);
            }
#pragma unroll
            for (int mt = 0; mt < 16; mt++) {
                short8 a = *(const short8*)&wlds[(size_t)(((kc * 16 + mt) * 64) + lane) * 8];
                // D[m=dim][n=node] — lane holds node=nl, dims mt*16 + q*4 + rg
                acc[mt] = __builtin_amdgcn_mfma_f32_16x16x32_bf16(a, b, acc[mt], 0, 0, 0);
            }
        }
        __syncthreads();   // all waves done reading W before we clobber LDS

        // Phase A: lane writes bf16x4 (4 consecutive dims of node nl) per mt
        char* wbase = pool + wave * (16 * LDSTRIDE);
#pragma unroll
        for (int mt = 0; mt < 16; mt++) {
            uint2 p;
            p.x = ((unsigned int)f2bf(acc[mt][1]) << 16) | f2bf(acc[mt][0]);
            p.y = ((unsigned int)f2bf(acc[mt][3]) << 16) | f2bf(acc[mt][2]);
            *(uint2*)(wbase + nl * LDSTRIDE + mt * 32 + q * 8) = p;
        }
        // Phase B: read row-contiguous, store 1 KB per instruction
#pragma unroll
        for (int i = 0; i < 8; i++) {
            int row = 2 * i + (lane >> 5);
            uint4 v = *(const uint4*)(wbase + row * LDSTRIDE + (lane & 31) * 16);
            int node = rowbase + row;
            if (node < N_NODES)
                *(uint4*)((char*)sup + (size_t)node * 512 + (lane & 31) * 16) = v;
        }
        __syncthreads();   // epilogue LDS reads done before next strip re-stages W
    }
}

// ---------------- CSR aggregation ----------------
// One wave per row. 4 lane-groups of 16 handle 4 edges concurrently;
// each lane covers 16 dims (2x dwordx4 gather). Cross-group combine by shuffle.
__global__ __launch_bounds__(256) void k_agg(const int* __restrict__ rs,
                                             const int2* __restrict__ csr,
                                             const unsigned short* __restrict__ sup,
                                             const float* __restrict__ bias,
                                             float* __restrict__ out) {
    int wave = threadIdx.x >> 6, lane = threadIdx.x & 63;
    int r = blockIdx.x * 4 + wave;
    int s = rs[r], e = rs[r + 1];
    int g = lane >> 4;          // edge subgroup 0..3
    int L = lane & 15;          // dim subgroup: dims [L*16, L*16+16)

    float acc[16];
#pragma unroll
    for (int j = 0; j < 16; j++) acc[j] = 0.f;

    int i = s;
    for (; i + 4 <= e; i += 4) {
        int2 ce = csr[i + g];
        float v = __int_as_float(ce.y);
        const uint4* sp = (const uint4*)(sup + (size_t)ce.x * DIM + L * 16);
        uint4 u0 = sp[0];
        uint4 u1 = sp[1];
        unsigned int uu[8] = {u0.x, u0.y, u0.z, u0.w, u1.x, u1.y, u1.z, u1.w};
#pragma unroll
        for (int k = 0; k < 8; k++) {
            acc[2 * k]     += v * __uint_as_float(uu[k] << 16);
            acc[2 * k + 1] += v * __uint_as_float(uu[k] & 0xFFFF0000u);
        }
    }
    {   // tail (<4 edges)
        int idx = i + g;
        if (idx < e) {
            int2 ce = csr[idx];
            float v = __int_as_float(ce.y);
            const uint4* sp = (const uint4*)(sup + (size_t)ce.x * DIM + L * 16);
            uint4 u0 = sp[0];
            uint4 u1 = sp[1];
            unsigned int uu[8] = {u0.x, u0.y, u0.z, u0.w, u1.x, u1.y, u1.z, u1.w};
#pragma unroll
            for (int k = 0; k < 8; k++) {
                acc[2 * k]     += v * __uint_as_float(uu[k] << 16);
                acc[2 * k + 1] += v * __uint_as_float(uu[k] & 0xFFFF0000u);
            }
        }
    }
    // combine groups: lanes {L, L+16, L+32, L+48} hold same dims
#pragma unroll
    for (int j = 0; j < 16; j++) {
        float x = acc[j];
        x += __shfl_down(x, 32, 64);
        x += __shfl_down(x, 16, 64);
        acc[j] = x;
    }
    if (lane < 16) {
        float4* op = (float4*)(out + (size_t)r * DIM + L * 16);
        const float4* bp = (const float4*)(bias + L * 16);
#pragma unroll
        for (int qq = 0; qq < 4; qq++) {
            float4 b = bp[qq];
            float4 o;
            o.x = acc[4 * qq]     + b.x;
            o.y = acc[4 * qq + 1] + b.y;
            o.z = acc[4 * qq + 2] + b.z;
            o.w = acc[4 * qq + 3] + b.w;
            op[qq] = o;
        }
    }
}

extern "C" void kernel_launch(void* const* d_in, const int* in_sizes, int n_in,
                              void* d_out, int out_size, void* d_ws, size_t ws_size,
                              hipStream_t stream) {
    const float* X    = (const float*)d_in[0];
    const int*   erow = (const int*)d_in[1];
    const int*   ecol = (const int*)d_in[2];
    const float* eval = (const float*)d_in[3];
    const float* W    = (const float*)d_in[4];
    const float* bias = (const float*)d_in[5];
    float* out = (float*)d_out;

    // Workspace layout IDENTICAL to the verified 818 µs baseline (no growth):
    // bcur (391 ints) lives in the unused tail of the bsum region (1024 ints,
    // only 98 used) — ints [128, 519).
    char* ws = (char*)d_ws;
    int*            rsb  = (int*)ws;                          // 102400 ints
    int*            cur  = (int*)(ws + 409600);               // 102400 ints (histogram)
    int*            bsum = (int*)(ws + 819200);               // 98 ints used of 1024
    int*            bcur = (int*)(ws + 819200) + 128;         // 391 ints (bsum tail)
    unsigned short* wp   = (unsigned short*)(ws + 823296);    // 65536 bf16
    int2*           csr  = (int2*)(ws + 954368);              // 3.2M int2 = 25.6 MB
    unsigned short* sup  = (unsigned short*)(ws + 26554368);  // 25.6M bf16 = 51.2 MB
    int2*           tmp  = (int2*)(ws + 26554368);            // aliases sup (dead until k_gemm)

    hipMemsetAsync(cur, 0, 409600, stream);
    k_hist<<<N_EDGES / 256, 256, 0, stream>>>(erow, cur);
    k_scan1<<<98, 1024, 0, stream>>>(cur, rsb, bsum);
    k_scan2<<<1, 128, 0, stream>>>(bsum);
    k_scanadd<<<98, 1024, 0, stream>>>(rsb, bsum);
    k_binit<<<1, 512, 0, stream>>>(rsb, bcur);
    k_bucket<<<256, 512, 0, stream>>>(erow, ecol, eval, bcur, tmp);
    k_place<<<NBUCK, 256, 0, stream>>>(rsb, tmp, csr);
    k_wpack<<<32, 256, 0, stream>>>(W, wp);
    k_gemm<<<256, 1024, 0, stream>>>(X, wp, sup);
    k_agg<<<N_NODES / 4, 256, 0, stream>>>(rsb, csr, sup, bias, out);
}